// Round 1
// baseline (3365.138 us; speedup 1.0000x reference)
//
#include <hip/hip_runtime.h>
#include <math.h>

#define D 64

__device__ __forceinline__ void atomAdd(float* p, float v) { unsafeAtomicAdd(p, v); }

// For 4 nodes per wave (lane = output dim o in 0..63):
//   yz[n][0:64]   = act(h[n]) @ Wm
//   yz[n][64:128] = act(h[n]) @ Bm
//   agg[n][0:64]  = act(h[n]) @ Wr + b   (initializes the scatter accumulator)
template <bool RELU>
__global__ __launch_bounds__(256) void transform64(
    const float* __restrict__ h, const float* __restrict__ Wm,
    const float* __restrict__ Bm, const float* __restrict__ Wr,
    const float* __restrict__ b, float* __restrict__ yz,
    float* __restrict__ agg, int n) {
  int wave = (blockIdx.x * 256 + threadIdx.x) >> 6;
  int lane = threadIdx.x & 63;
  int nb = wave << 2;
  if (nb >= n) return;
  float hv[4];
#pragma unroll
  for (int j = 0; j < 4; ++j) {
    int nn = nb + j;
    float v = (nn < n) ? h[(size_t)nn * D + lane] : 0.f;
    if (RELU) v = fmaxf(v, 0.f);
    hv[j] = v;
  }
  float ay[4] = {0.f, 0.f, 0.f, 0.f};
  float az[4] = {0.f, 0.f, 0.f, 0.f};
  float ar[4] = {0.f, 0.f, 0.f, 0.f};
#pragma unroll 8
  for (int k = 0; k < D; ++k) {
    float wm = Wm[k * D + lane];
    float wb = Bm[k * D + lane];
    float wr = Wr[k * D + lane];
#pragma unroll
    for (int j = 0; j < 4; ++j) {
      float hk = __shfl(hv[j], k, 64);
      ay[j] = fmaf(hk, wm, ay[j]);
      az[j] = fmaf(hk, wb, az[j]);
      ar[j] = fmaf(hk, wr, ar[j]);
    }
  }
  float bb = b[lane];
#pragma unroll
  for (int j = 0; j < 4; ++j) {
    int nn = nb + j;
    if (nn >= n) break;
    yz[(size_t)nn * 128 + lane] = ay[j];
    yz[(size_t)nn * 128 + 64 + lane] = az[j];
    agg[(size_t)nn * D + lane] = ar[j] + bb;
  }
}

// Layer 3 transform: outputs 12 values/node. lane<12: sel=lane>>2 picks
// (0)Wm,(1)Bm,(2)Wr; o=lane&3 is the output column. All W3 are [64,4] row-major.
__global__ __launch_bounds__(256) void transform3(
    const float* __restrict__ h, const float* __restrict__ Wm,
    const float* __restrict__ Bm, const float* __restrict__ Wr,
    const float* __restrict__ b, float* __restrict__ yz3,
    float* __restrict__ agg3, int n) {
  int wave = (blockIdx.x * 256 + threadIdx.x) >> 6;
  int lane = threadIdx.x & 63;
  int nb = wave << 2;
  if (nb >= n) return;
  int sel = lane >> 2;
  int o = lane & 3;
  const float* wcol = (sel == 0) ? Wm : (sel == 1) ? Bm : Wr;
  float hv[4];
#pragma unroll
  for (int j = 0; j < 4; ++j) {
    int nn = nb + j;
    float v = (nn < n) ? h[(size_t)nn * D + lane] : 0.f;
    hv[j] = fmaxf(v, 0.f);  // input to layer 3 is always relu'd
  }
  float acc[4] = {0.f, 0.f, 0.f, 0.f};
#pragma unroll 8
  for (int k = 0; k < D; ++k) {
    float w = wcol[k * 4 + o];
#pragma unroll
    for (int j = 0; j < 4; ++j) {
      float hk = __shfl(hv[j], k, 64);
      acc[j] = fmaf(hk, w, acc[j]);
    }
  }
  if (sel < 3) {
#pragma unroll
    for (int j = 0; j < 4; ++j) {
      int nn = nb + j;
      if (nn >= n) break;
      if (sel == 0)
        yz3[(size_t)nn * 8 + o] = acc[j];
      else if (sel == 1)
        yz3[(size_t)nn * 8 + 4 + o] = acc[j];
      else
        agg3[(size_t)nn * 4 + o] = acc[j] + b[o];
    }
  }
}

// Edge scatter, layers 1-2: 16 threads per edge, each handles one float4 of
// the 64-wide message msg = e*y[src] + z[src]; atomically adds into agg[dst].
__global__ __launch_bounds__(256) void scatter64(
    const int* __restrict__ ei, const float* __restrict__ ea,
    const float* __restrict__ yz, float* __restrict__ agg, int ne) {
  int idx = blockIdx.x * 256 + threadIdx.x;
  int e = idx >> 4;
  if (e >= ne) return;
  int q = idx & 15;
  int src = ei[e];
  int dst = ei[ne + e];
  float ev = ea[e];
  const float4* yzv = (const float4*)yz;
  float4 y = yzv[(size_t)src * 32 + q];
  float4 z = yzv[(size_t)src * 32 + 16 + q];
  float* out = agg + (size_t)dst * 64 + q * 4;
  atomAdd(out + 0, fmaf(ev, y.x, z.x));
  atomAdd(out + 1, fmaf(ev, y.y, z.y));
  atomAdd(out + 2, fmaf(ev, y.z, z.z));
  atomAdd(out + 3, fmaf(ev, y.w, z.w));
}

// Edge scatter, layer 3: one thread per edge, 4-wide message.
__global__ __launch_bounds__(256) void scatter3(
    const int* __restrict__ ei, const float* __restrict__ ea,
    const float* __restrict__ yz3, float* __restrict__ agg3, int ne) {
  int e = blockIdx.x * 256 + threadIdx.x;
  if (e >= ne) return;
  int src = ei[e];
  int dst = ei[ne + e];
  float ev = ea[e];
  const float4* v = (const float4*)yz3;
  float4 y = v[(size_t)src * 2];
  float4 z = v[(size_t)src * 2 + 1];
  float* out = agg3 + (size_t)dst * 4;
  atomAdd(out + 0, fmaf(ev, y.x, z.x));
  atomAdd(out + 1, fmaf(ev, y.y, z.y));
  atomAdd(out + 2, fmaf(ev, y.z, z.z));
  atomAdd(out + 3, fmaf(ev, y.w, z.w));
}

__global__ __launch_bounds__(256) void logsm(const float* __restrict__ agg3,
                                             float* __restrict__ out, int n) {
  int i = blockIdx.x * 256 + threadIdx.x;
  if (i >= n) return;
  float4 v = ((const float4*)agg3)[i];
  float m = fmaxf(fmaxf(v.x, v.y), fmaxf(v.z, v.w));
  float s = expf(v.x - m) + expf(v.y - m) + expf(v.z - m) + expf(v.w - m);
  float ls = m + logf(s);
  float4 r;
  r.x = v.x - ls;
  r.y = v.y - ls;
  r.z = v.z - ls;
  r.w = v.w - ls;
  ((float4*)out)[i] = r;
}

extern "C" void kernel_launch(void* const* d_in, const int* in_sizes, int n_in,
                              void* d_out, int out_size, void* d_ws, size_t ws_size,
                              hipStream_t stream) {
  const float* x = (const float*)d_in[0];
  const int* ei = (const int*)d_in[1];
  const float* ea = (const float*)d_in[2];
  const float* We1 = (const float*)d_in[3];
  const float* be1 = (const float*)d_in[4];
  const float* Wr1 = (const float*)d_in[5];
  const float* b1 = (const float*)d_in[6];
  const float* We2 = (const float*)d_in[7];
  const float* be2 = (const float*)d_in[8];
  const float* Wr2 = (const float*)d_in[9];
  const float* b2 = (const float*)d_in[10];
  const float* We3 = (const float*)d_in[11];
  const float* be3 = (const float*)d_in[12];
  const float* Wr3 = (const float*)d_in[13];
  const float* b3 = (const float*)d_in[14];

  const int N = in_sizes[0] / D;  // 100000
  const int E = in_sizes[2];      // 1600000

  float* ws = (float*)d_ws;
  float* yz = ws;                              // N*128 floats (reused per layer; N*8 for layer 3)
  float* agg1 = ws + (size_t)N * 128;          // N*64
  float* agg2 = agg1 + (size_t)N * 64;         // N*64
  float* agg3 = agg2 + (size_t)N * 64;         // N*4
  float* out = (float*)d_out;

  int waves = (N + 3) / 4;
  int tblocks = (waves + 3) / 4;                         // 256 thr = 4 waves/block
  int s64blocks = (int)(((long long)E * 16 + 255) / 256);
  int s3blocks = (E + 255) / 256;
  int nblocks = (N + 255) / 256;

  // Layer 1: x -> agg1
  transform64<false><<<tblocks, 256, 0, stream>>>(x, We1, be1, Wr1, b1, yz, agg1, N);
  scatter64<<<s64blocks, 256, 0, stream>>>(ei, ea, yz, agg1, E);
  // Layer 2: relu(agg1) -> agg2
  transform64<true><<<tblocks, 256, 0, stream>>>(agg1, We2, be2, Wr2, b2, yz, agg2, N);
  scatter64<<<s64blocks, 256, 0, stream>>>(ei, ea, yz, agg2, E);
  // Layer 3: relu(agg2) -> agg3 (4-wide)
  transform3<<<tblocks, 256, 0, stream>>>(agg2, We3, be3, Wr3, b3, yz, agg3, N);
  scatter3<<<s3blocks, 256, 0, stream>>>(ei, ea, yz, agg3, E);
  // log_softmax
  logsm<<<nblocks, 256, 0, stream>>>(agg3, out, N);
}

// Round 2
// 783.685 us; speedup vs baseline: 4.2940x; 4.2940x over previous
//
#include <hip/hip_runtime.h>
#include <math.h>

#define D 64
#define SCAN_CHUNK 1024

// ---------------- transforms (dense per-node GEMMs, wave = 64 output dims) ---

// For 4 nodes per wave (lane = output dim o in 0..63):
//   yz[n][0:64]   = act(h[n]) @ Wm
//   yz[n][64:128] = act(h[n]) @ Bm
//   agg[n][0:64]  = act(h[n]) @ Wr + b   (initializes the gather accumulator)
template <bool RELU>
__global__ __launch_bounds__(256) void transform64(
    const float* __restrict__ h, const float* __restrict__ Wm,
    const float* __restrict__ Bm, const float* __restrict__ Wr,
    const float* __restrict__ b, float* __restrict__ yz,
    float* __restrict__ agg, int n) {
  int wave = (blockIdx.x * 256 + threadIdx.x) >> 6;
  int lane = threadIdx.x & 63;
  int nb = wave << 2;
  if (nb >= n) return;
  float hv[4];
#pragma unroll
  for (int j = 0; j < 4; ++j) {
    int nn = nb + j;
    float v = (nn < n) ? h[(size_t)nn * D + lane] : 0.f;
    if (RELU) v = fmaxf(v, 0.f);
    hv[j] = v;
  }
  float ay[4] = {0.f, 0.f, 0.f, 0.f};
  float az[4] = {0.f, 0.f, 0.f, 0.f};
  float ar[4] = {0.f, 0.f, 0.f, 0.f};
#pragma unroll 8
  for (int k = 0; k < D; ++k) {
    float wm = Wm[k * D + lane];
    float wb = Bm[k * D + lane];
    float wr = Wr[k * D + lane];
#pragma unroll
    for (int j = 0; j < 4; ++j) {
      float hk = __shfl(hv[j], k, 64);
      ay[j] = fmaf(hk, wm, ay[j]);
      az[j] = fmaf(hk, wb, az[j]);
      ar[j] = fmaf(hk, wr, ar[j]);
    }
  }
  float bb = b[lane];
#pragma unroll
  for (int j = 0; j < 4; ++j) {
    int nn = nb + j;
    if (nn >= n) break;
    yz[(size_t)nn * 128 + lane] = ay[j];
    yz[(size_t)nn * 128 + 64 + lane] = az[j];
    agg[(size_t)nn * D + lane] = ar[j] + bb;
  }
}

// Layer 3 transform: 12 outputs/node. sel=lane>>2 picks (0)Wm,(1)Bm,(2)Wr;
// o=lane&3 is the output column. All layer-3 W are [64,4] row-major.
__global__ __launch_bounds__(256) void transform3(
    const float* __restrict__ h, const float* __restrict__ Wm,
    const float* __restrict__ Bm, const float* __restrict__ Wr,
    const float* __restrict__ b, float* __restrict__ yz3,
    float* __restrict__ agg3, int n) {
  int wave = (blockIdx.x * 256 + threadIdx.x) >> 6;
  int lane = threadIdx.x & 63;
  int nb = wave << 2;
  if (nb >= n) return;
  int sel = lane >> 2;
  int o = lane & 3;
  const float* wcol = (sel == 0) ? Wm : (sel == 1) ? Bm : Wr;
  float hv[4];
#pragma unroll
  for (int j = 0; j < 4; ++j) {
    int nn = nb + j;
    float v = (nn < n) ? h[(size_t)nn * D + lane] : 0.f;
    hv[j] = fmaxf(v, 0.f);  // layer-3 input is always relu'd
  }
  float acc[4] = {0.f, 0.f, 0.f, 0.f};
#pragma unroll 8
  for (int k = 0; k < D; ++k) {
    float w = wcol[k * 4 + o];
#pragma unroll
    for (int j = 0; j < 4; ++j) {
      float hk = __shfl(hv[j], k, 64);
      acc[j] = fmaf(hk, w, acc[j]);
    }
  }
  if (sel < 3) {
#pragma unroll
    for (int j = 0; j < 4; ++j) {
      int nn = nb + j;
      if (nn >= n) break;
      if (sel == 0)
        yz3[(size_t)nn * 8 + o] = acc[j];
      else if (sel == 1)
        yz3[(size_t)nn * 8 + 4 + o] = acc[j];
      else
        agg3[(size_t)nn * 4 + o] = acc[j] + b[o];
    }
  }
}

// ---------------- CSR build: histogram -> 3-kernel exclusive scan -> fill ----

__global__ __launch_bounds__(256) void k_hist(const int* __restrict__ ei,
                                              int* __restrict__ deg, int ne) {
  int e = blockIdx.x * 256 + threadIdx.x;
  if (e >= ne) return;
  atomicAdd(&deg[ei[ne + e]], 1);
}

__global__ __launch_bounds__(256) void k_reduce(const int* __restrict__ deg,
                                                int* __restrict__ blockSums, int n) {
  int base = blockIdx.x * SCAN_CHUNK;
  int t = threadIdx.x;
  int s = 0;
  for (int j = t; j < SCAN_CHUNK; j += 256) {
    int gi = base + j;
    if (gi < n) s += deg[gi];
  }
#pragma unroll
  for (int d = 32; d; d >>= 1) s += __shfl_down(s, d, 64);
  __shared__ int ws4[4];
  int lane = t & 63, wid = t >> 6;
  if (lane == 0) ws4[wid] = s;
  __syncthreads();
  if (t == 0) blockSums[blockIdx.x] = ws4[0] + ws4[1] + ws4[2] + ws4[3];
}

__global__ void k_scan_sums(const int* __restrict__ blockSums,
                            int* __restrict__ blockOff, int nb) {
  if (threadIdx.x == 0 && blockIdx.x == 0) {
    int a = 0;
    for (int i = 0; i < nb; ++i) { blockOff[i] = a; a += blockSums[i]; }
  }
}

__global__ __launch_bounds__(256) void k_scan_add(
    const int* __restrict__ deg, const int* __restrict__ blockOff,
    int* __restrict__ off, int* __restrict__ cursor, int n, int nTotal) {
  __shared__ int waveSums[4];
  int t = threadIdx.x;
  int gi = blockIdx.x * SCAN_CHUNK + t * 4;
  int v[4];
#pragma unroll
  for (int j = 0; j < 4; ++j) v[j] = (gi + j < n) ? deg[gi + j] : 0;
  int t1 = v[0] + v[1];
  int t2 = t1 + v[2];
  int s = t2 + v[3];
  int lane = t & 63, wid = t >> 6;
  int inc = s;
#pragma unroll
  for (int d = 1; d < 64; d <<= 1) {
    int u = __shfl_up(inc, d, 64);
    if (lane >= d) inc += u;
  }
  if (lane == 63) waveSums[wid] = inc;
  __syncthreads();
  if (t == 0) {
    int a = 0;
#pragma unroll
    for (int w = 0; w < 4; ++w) { int tmp = waveSums[w]; waveSums[w] = a; a += tmp; }
  }
  __syncthreads();
  int thrOff = blockOff[blockIdx.x] + waveSums[wid] + (inc - s);
  int pre[4] = {0, v[0], t1, t2};
#pragma unroll
  for (int j = 0; j < 4; ++j)
    if (gi + j < n) {
      off[gi + j] = thrOff + pre[j];
      cursor[gi + j] = thrOff + pre[j];
    }
  if (blockIdx.x == 0 && t == 0) off[n] = nTotal;
}

__global__ __launch_bounds__(256) void k_fill(
    const int* __restrict__ ei, const float* __restrict__ ea,
    int* __restrict__ cursor, int* __restrict__ srcS, float* __restrict__ eaS,
    int ne) {
  int e = blockIdx.x * 256 + threadIdx.x;
  if (e >= ne) return;
  int d = ei[ne + e];
  int pos = atomicAdd(&cursor[d], 1);
  srcS[pos] = ei[e];
  eaS[pos] = ea[e];
}

// ---------------- gather-aggregate (conflict-free, one write per node) ------

// One wave per node; lane = feature dim. acc starts at the root+bias term.
__global__ __launch_bounds__(256) void gather64(
    const int* __restrict__ off, const int* __restrict__ srcS,
    const float* __restrict__ eaS, const float* __restrict__ yz,
    float* __restrict__ agg, int n) {
  int node = (blockIdx.x * 256 + threadIdx.x) >> 6;
  int lane = threadIdx.x & 63;
  if (node >= n) return;
  int j = off[node];
  int jend = off[node + 1];
  float acc = agg[(size_t)node * 64 + lane];
#pragma unroll 1
  for (; j + 1 < jend; j += 2) {
    int a = srcS[j], bsrc = srcS[j + 1];
    float e0 = eaS[j], e1 = eaS[j + 1];
    const float* ra = yz + (size_t)a * 128;
    const float* rb = yz + (size_t)bsrc * 128;
    float y0 = ra[lane], z0 = ra[64 + lane];
    float y1 = rb[lane], z1 = rb[64 + lane];
    acc += fmaf(e0, y0, z0) + fmaf(e1, y1, z1);
  }
  if (j < jend) {
    int a = srcS[j];
    float e0 = eaS[j];
    const float* ra = yz + (size_t)a * 128;
    acc += fmaf(e0, ra[lane], ra[64 + lane]);
  }
  agg[(size_t)node * 64 + lane] = acc;
}

// Layer 3: 4 lanes per node (o = class), fused log_softmax across the group.
__global__ __launch_bounds__(256) void gather4_logsm(
    const int* __restrict__ off, const int* __restrict__ srcS,
    const float* __restrict__ eaS, const float* __restrict__ yz3,
    const float* __restrict__ agg3, float* __restrict__ out, int n) {
  int idx = blockIdx.x * 256 + threadIdx.x;
  int node = idx >> 2;
  int o = idx & 3;
  if (node >= n) return;
  int j = off[node];
  int jend = off[node + 1];
  float acc = agg3[(size_t)node * 4 + o];
#pragma unroll 1
  for (; j < jend; ++j) {
    int a = srcS[j];
    float e0 = eaS[j];
    acc += fmaf(e0, yz3[(size_t)a * 8 + o], yz3[(size_t)a * 8 + 4 + o]);
  }
  float m = acc;
  m = fmaxf(m, __shfl_xor(m, 1, 4));
  m = fmaxf(m, __shfl_xor(m, 2, 4));
  float s = expf(acc - m);
  s += __shfl_xor(s, 1, 4);
  s += __shfl_xor(s, 2, 4);
  out[(size_t)node * 4 + o] = acc - m - logf(s);
}

// ---------------- launch -----------------------------------------------------

extern "C" void kernel_launch(void* const* d_in, const int* in_sizes, int n_in,
                              void* d_out, int out_size, void* d_ws, size_t ws_size,
                              hipStream_t stream) {
  const float* x = (const float*)d_in[0];
  const int* ei = (const int*)d_in[1];
  const float* ea = (const float*)d_in[2];
  const float* We1 = (const float*)d_in[3];
  const float* be1 = (const float*)d_in[4];
  const float* Wr1 = (const float*)d_in[5];
  const float* b1 = (const float*)d_in[6];
  const float* We2 = (const float*)d_in[7];
  const float* be2 = (const float*)d_in[8];
  const float* Wr2 = (const float*)d_in[9];
  const float* b2 = (const float*)d_in[10];
  const float* We3 = (const float*)d_in[11];
  const float* be3 = (const float*)d_in[12];
  const float* Wr3 = (const float*)d_in[13];
  const float* b3 = (const float*)d_in[14];

  const int N = in_sizes[0] / D;  // 100000
  const int E = in_sizes[2];      // 1600000
  const int nb = (N + SCAN_CHUNK - 1) / SCAN_CHUNK;  // 98 scan blocks

  float* ws = (float*)d_ws;
  float* yz = ws;                          // N*128 (reused per layer; N*8 for L3)
  float* agg1 = yz + (size_t)N * 128;      // N*64
  float* agg2 = agg1 + (size_t)N * 64;     // N*64
  float* agg3 = agg2 + (size_t)N * 64;     // N*4
  int* off = (int*)(agg3 + (size_t)N * 4); // N+1
  int* cursor = off + (N + 1);             // N
  int* blockSums = cursor + N;             // 128
  int* blockOff = blockSums + 128;         // 128
  int* srcS = blockOff + 128;              // E
  float* eaS = (float*)(srcS + E);         // E
  int* deg = (int*)(eaS + E);              // N
  float* out = (float*)d_out;

  int waves = (N + 3) / 4;
  int tblocks = (waves + 3) / 4;           // transform: 4 waves/block
  int eblocks = (E + 255) / 256;
  int g64blocks = (int)(((long long)N * 64 + 255) / 256);
  int g4blocks = (int)(((long long)N * 4 + 255) / 256);

  // ---- CSR build (dst-sorted edge permutation) ----
  hipMemsetAsync(deg, 0, (size_t)N * 4, stream);
  k_hist<<<eblocks, 256, 0, stream>>>(ei, deg, E);
  k_reduce<<<nb, 256, 0, stream>>>(deg, blockSums, N);
  k_scan_sums<<<1, 64, 0, stream>>>(blockSums, blockOff, nb);
  k_scan_add<<<nb, 256, 0, stream>>>(deg, blockOff, off, cursor, N, E);
  k_fill<<<eblocks, 256, 0, stream>>>(ei, ea, cursor, srcS, eaS, E);

  // ---- Layer 1: x -> agg1 ----
  transform64<false><<<tblocks, 256, 0, stream>>>(x, We1, be1, Wr1, b1, yz, agg1, N);
  gather64<<<g64blocks, 256, 0, stream>>>(off, srcS, eaS, yz, agg1, N);
  // ---- Layer 2: relu(agg1) -> agg2 ----
  transform64<true><<<tblocks, 256, 0, stream>>>(agg1, We2, be2, Wr2, b2, yz, agg2, N);
  gather64<<<g64blocks, 256, 0, stream>>>(off, srcS, eaS, yz, agg2, N);
  // ---- Layer 3: relu(agg2) -> out (fused log_softmax) ----
  transform3<<<tblocks, 256, 0, stream>>>(agg2, We3, be3, Wr3, b3, yz, agg3, N);
  gather4_logsm<<<g4blocks, 256, 0, stream>>>(off, srcS, eaS, yz, agg3, out, N);
}

// Round 3
// 716.060 us; speedup vs baseline: 4.6995x; 1.0944x over previous
//
#include <hip/hip_runtime.h>
#include <math.h>

#define D 64
#define SCAN_CHUNK 1024

// ---- bf16 pack helpers (RNE) ----
__device__ __forceinline__ unsigned short f2bf(float f) {
  unsigned u = __float_as_uint(f);
  unsigned r = (u + 0x7fff + ((u >> 16) & 1)) >> 16;
  return (unsigned short)r;
}
__device__ __forceinline__ float bfLo(unsigned p) { return __uint_as_float(p << 16); }
__device__ __forceinline__ float bfHi(unsigned p) { return __uint_as_float(p & 0xffff0000u); }
__device__ __forceinline__ unsigned packYZ(float y, float z) {
  return (unsigned)f2bf(y) | ((unsigned)f2bf(z) << 16);
}

// ---------------- transforms (dense per-node GEMMs, wave = 64 output dims) ---

// For 4 nodes per wave (lane = output dim o in 0..63):
//   yzp[n][lane] = pack(bf16(act(h)@Wm), bf16(act(h)@Bm))
//   agg[n][lane] = act(h[n]) @ Wr + b   (initializes the gather accumulator)
template <bool RELU>
__global__ __launch_bounds__(256) void transform64(
    const float* __restrict__ h, const float* __restrict__ Wm,
    const float* __restrict__ Bm, const float* __restrict__ Wr,
    const float* __restrict__ b, unsigned* __restrict__ yzp,
    float* __restrict__ agg, int n) {
  int wave = (blockIdx.x * 256 + threadIdx.x) >> 6;
  int lane = threadIdx.x & 63;
  int nb = wave << 2;
  if (nb >= n) return;
  float hv[4];
#pragma unroll
  for (int j = 0; j < 4; ++j) {
    int nn = nb + j;
    float v = (nn < n) ? h[(size_t)nn * D + lane] : 0.f;
    if (RELU) v = fmaxf(v, 0.f);
    hv[j] = v;
  }
  float ay[4] = {0.f, 0.f, 0.f, 0.f};
  float az[4] = {0.f, 0.f, 0.f, 0.f};
  float ar[4] = {0.f, 0.f, 0.f, 0.f};
#pragma unroll 8
  for (int k = 0; k < D; ++k) {
    float wm = Wm[k * D + lane];
    float wb = Bm[k * D + lane];
    float wr = Wr[k * D + lane];
#pragma unroll
    for (int j = 0; j < 4; ++j) {
      float hk = __shfl(hv[j], k, 64);
      ay[j] = fmaf(hk, wm, ay[j]);
      az[j] = fmaf(hk, wb, az[j]);
      ar[j] = fmaf(hk, wr, ar[j]);
    }
  }
  float bb = b[lane];
#pragma unroll
  for (int j = 0; j < 4; ++j) {
    int nn = nb + j;
    if (nn >= n) break;
    yzp[(size_t)nn * 64 + lane] = packYZ(ay[j], az[j]);
    agg[(size_t)nn * D + lane] = ar[j] + bb;
  }
}

// Layer 3 transform: lanes 0..3 accumulate y,z,r for o=lane (4 classes);
// all lanes provide hv via shfl. W3 are [64,4] row-major.
__global__ __launch_bounds__(256) void transform3(
    const float* __restrict__ h, const float* __restrict__ Wm,
    const float* __restrict__ Bm, const float* __restrict__ Wr,
    const float* __restrict__ b, unsigned* __restrict__ yz3p,
    float* __restrict__ agg3, int n) {
  int wave = (blockIdx.x * 256 + threadIdx.x) >> 6;
  int lane = threadIdx.x & 63;
  int nb = wave << 2;
  if (nb >= n) return;
  int o = lane & 3;
  float hv[4];
#pragma unroll
  for (int j = 0; j < 4; ++j) {
    int nn = nb + j;
    float v = (nn < n) ? h[(size_t)nn * D + lane] : 0.f;
    hv[j] = fmaxf(v, 0.f);  // layer-3 input is always relu'd
  }
  float accY[4] = {0.f, 0.f, 0.f, 0.f};
  float accZ[4] = {0.f, 0.f, 0.f, 0.f};
  float accR[4] = {0.f, 0.f, 0.f, 0.f};
#pragma unroll 8
  for (int k = 0; k < D; ++k) {
    float wm = Wm[k * 4 + o];
    float wb = Bm[k * 4 + o];
    float wr = Wr[k * 4 + o];
#pragma unroll
    for (int j = 0; j < 4; ++j) {
      float hk = __shfl(hv[j], k, 64);
      accY[j] = fmaf(hk, wm, accY[j]);
      accZ[j] = fmaf(hk, wb, accZ[j]);
      accR[j] = fmaf(hk, wr, accR[j]);
    }
  }
  if (lane < 4) {
    float bb = b[o];
#pragma unroll
    for (int j = 0; j < 4; ++j) {
      int nn = nb + j;
      if (nn >= n) break;
      yz3p[(size_t)nn * 4 + o] = packYZ(accY[j], accZ[j]);
      agg3[(size_t)nn * 4 + o] = accR[j] + bb;
    }
  }
}

// ---------------- CSR build: histogram -> 3-kernel exclusive scan -> fill ----

__global__ __launch_bounds__(256) void k_hist(const int* __restrict__ ei,
                                              int* __restrict__ deg, int ne) {
  int e = blockIdx.x * 256 + threadIdx.x;
  if (e >= ne) return;
  atomicAdd(&deg[ei[ne + e]], 1);
}

__global__ __launch_bounds__(256) void k_reduce(const int* __restrict__ deg,
                                                int* __restrict__ blockSums, int n) {
  int base = blockIdx.x * SCAN_CHUNK;
  int t = threadIdx.x;
  int s = 0;
  for (int j = t; j < SCAN_CHUNK; j += 256) {
    int gi = base + j;
    if (gi < n) s += deg[gi];
  }
#pragma unroll
  for (int d = 32; d; d >>= 1) s += __shfl_down(s, d, 64);
  __shared__ int ws4[4];
  int lane = t & 63, wid = t >> 6;
  if (lane == 0) ws4[wid] = s;
  __syncthreads();
  if (t == 0) blockSums[blockIdx.x] = ws4[0] + ws4[1] + ws4[2] + ws4[3];
}

__global__ void k_scan_sums(const int* __restrict__ blockSums,
                            int* __restrict__ blockOff, int nb) {
  if (threadIdx.x == 0 && blockIdx.x == 0) {
    int a = 0;
    for (int i = 0; i < nb; ++i) { blockOff[i] = a; a += blockSums[i]; }
  }
}

__global__ __launch_bounds__(256) void k_scan_add(
    const int* __restrict__ deg, const int* __restrict__ blockOff,
    int* __restrict__ off, int* __restrict__ cursor, int n, int nTotal) {
  __shared__ int waveSums[4];
  int t = threadIdx.x;
  int gi = blockIdx.x * SCAN_CHUNK + t * 4;
  int v[4];
#pragma unroll
  for (int j = 0; j < 4; ++j) v[j] = (gi + j < n) ? deg[gi + j] : 0;
  int t1 = v[0] + v[1];
  int t2 = t1 + v[2];
  int s = t2 + v[3];
  int lane = t & 63, wid = t >> 6;
  int inc = s;
#pragma unroll
  for (int d = 1; d < 64; d <<= 1) {
    int u = __shfl_up(inc, d, 64);
    if (lane >= d) inc += u;
  }
  if (lane == 63) waveSums[wid] = inc;
  __syncthreads();
  if (t == 0) {
    int a = 0;
#pragma unroll
    for (int w = 0; w < 4; ++w) { int tmp = waveSums[w]; waveSums[w] = a; a += tmp; }
  }
  __syncthreads();
  int thrOff = blockOff[blockIdx.x] + waveSums[wid] + (inc - s);
  int pre[4] = {0, v[0], t1, t2};
#pragma unroll
  for (int j = 0; j < 4; ++j)
    if (gi + j < n) {
      off[gi + j] = thrOff + pre[j];
      cursor[gi + j] = thrOff + pre[j];
    }
  if (blockIdx.x == 0 && t == 0) off[n] = nTotal;
}

// Single 8B store per edge: (src, ea-bits)
__global__ __launch_bounds__(256) void k_fill(
    const int* __restrict__ ei, const float* __restrict__ ea,
    int* __restrict__ cursor, uint2* __restrict__ edgeS, int ne) {
  int e = blockIdx.x * 256 + threadIdx.x;
  if (e >= ne) return;
  int d = ei[ne + e];
  int pos = atomicAdd(&cursor[d], 1);
  edgeS[pos] = make_uint2((unsigned)ei[e], __float_as_uint(ea[e]));
}

// ---------------- gather-aggregate (conflict-free, one write per node) ------

// One wave per node; lane = feature dim. acc starts at the root+bias term.
// Per edge: one broadcast uint2 (src, e) + one coalesced 4B/lane row read.
__global__ __launch_bounds__(256) void gather64(
    const int* __restrict__ off, const uint2* __restrict__ edgeS,
    const unsigned* __restrict__ yzp, float* __restrict__ agg, int n) {
  int node = (blockIdx.x * 256 + threadIdx.x) >> 6;
  int lane = threadIdx.x & 63;
  if (node >= n) return;
  int j = off[node];
  int jend = off[node + 1];
  float acc = agg[(size_t)node * 64 + lane];
#pragma unroll 1
  for (; j + 1 < jend; j += 2) {
    uint2 e0 = edgeS[j], e1 = edgeS[j + 1];
    unsigned p0 = yzp[(size_t)e0.x * 64 + lane];
    unsigned p1 = yzp[(size_t)e1.x * 64 + lane];
    acc += fmaf(__uint_as_float(e0.y), bfLo(p0), bfHi(p0));
    acc += fmaf(__uint_as_float(e1.y), bfLo(p1), bfHi(p1));
  }
  if (j < jend) {
    uint2 e0 = edgeS[j];
    unsigned p0 = yzp[(size_t)e0.x * 64 + lane];
    acc += fmaf(__uint_as_float(e0.y), bfLo(p0), bfHi(p0));
  }
  agg[(size_t)node * 64 + lane] = acc;
}

// Layer 3: 4 lanes per node (o = class), fused log_softmax across the group.
__global__ __launch_bounds__(256) void gather4_logsm(
    const int* __restrict__ off, const uint2* __restrict__ edgeS,
    const unsigned* __restrict__ yz3p, const float* __restrict__ agg3,
    float* __restrict__ out, int n) {
  int idx = blockIdx.x * 256 + threadIdx.x;
  int node = idx >> 2;
  int o = idx & 3;
  if (node >= n) return;
  int j = off[node];
  int jend = off[node + 1];
  float acc = agg3[(size_t)node * 4 + o];
#pragma unroll 1
  for (; j < jend; ++j) {
    uint2 ed = edgeS[j];
    unsigned p = yz3p[(size_t)ed.x * 4 + o];
    acc += fmaf(__uint_as_float(ed.y), bfLo(p), bfHi(p));
  }
  float m = acc;
  m = fmaxf(m, __shfl_xor(m, 1, 4));
  m = fmaxf(m, __shfl_xor(m, 2, 4));
  float s = expf(acc - m);
  s += __shfl_xor(s, 1, 4);
  s += __shfl_xor(s, 2, 4);
  out[(size_t)node * 4 + o] = acc - m - logf(s);
}

// ---------------- launch -----------------------------------------------------

extern "C" void kernel_launch(void* const* d_in, const int* in_sizes, int n_in,
                              void* d_out, int out_size, void* d_ws, size_t ws_size,
                              hipStream_t stream) {
  const float* x = (const float*)d_in[0];
  const int* ei = (const int*)d_in[1];
  const float* ea = (const float*)d_in[2];
  const float* We1 = (const float*)d_in[3];
  const float* be1 = (const float*)d_in[4];
  const float* Wr1 = (const float*)d_in[5];
  const float* b1 = (const float*)d_in[6];
  const float* We2 = (const float*)d_in[7];
  const float* be2 = (const float*)d_in[8];
  const float* Wr2 = (const float*)d_in[9];
  const float* b2 = (const float*)d_in[10];
  const float* We3 = (const float*)d_in[11];
  const float* be3 = (const float*)d_in[12];
  const float* Wr3 = (const float*)d_in[13];
  const float* b3 = (const float*)d_in[14];

  const int N = in_sizes[0] / D;  // 100000
  const int E = in_sizes[2];      // 1600000
  const int nb = (N + SCAN_CHUNK - 1) / SCAN_CHUNK;

  // ws layout (edgeS first for 8B alignment)
  char* ws = (char*)d_ws;
  uint2* edgeS = (uint2*)ws;                               // E * 8B
  unsigned* yzp = (unsigned*)(ws + (size_t)E * 8);         // N*64 * 4B
  float* agg1 = (float*)((char*)yzp + (size_t)N * 64 * 4); // N*64
  float* agg2 = agg1 + (size_t)N * 64;                     // N*64
  float* agg3 = agg2 + (size_t)N * 64;                     // N*4
  unsigned* yz3p = (unsigned*)(agg3 + (size_t)N * 4);      // N*4
  int* off = (int*)(yz3p + (size_t)N * 4);                 // N+1
  int* cursor = off + (N + 1);                             // N
  int* deg = cursor + N;                                   // N
  int* blockSums = deg + N;                                // 128
  int* blockOff = blockSums + 128;                         // 128
  float* out = (float*)d_out;

  int waves = (N + 3) / 4;
  int tblocks = (waves + 3) / 4;  // transform: 4 waves/block
  int eblocks = (E + 255) / 256;
  int g64blocks = (int)(((long long)N * 64 + 255) / 256);
  int g4blocks = (int)(((long long)N * 4 + 255) / 256);

  // ---- CSR build (dst-sorted edge permutation) ----
  hipMemsetAsync(deg, 0, (size_t)N * 4, stream);
  k_hist<<<eblocks, 256, 0, stream>>>(ei, deg, E);
  k_reduce<<<nb, 256, 0, stream>>>(deg, blockSums, N);
  k_scan_sums<<<1, 64, 0, stream>>>(blockSums, blockOff, nb);
  k_scan_add<<<nb, 256, 0, stream>>>(deg, blockOff, off, cursor, N, E);
  k_fill<<<eblocks, 256, 0, stream>>>(ei, ea, cursor, edgeS, E);

  // ---- Layer 1: x -> agg1 ----
  transform64<false><<<tblocks, 256, 0, stream>>>(x, We1, be1, Wr1, b1, yzp, agg1, N);
  gather64<<<g64blocks, 256, 0, stream>>>(off, edgeS, yzp, agg1, N);
  // ---- Layer 2: relu(agg1) -> agg2 ----
  transform64<true><<<tblocks, 256, 0, stream>>>(agg1, We2, be2, Wr2, b2, yzp, agg2, N);
  gather64<<<g64blocks, 256, 0, stream>>>(off, edgeS, yzp, agg2, N);
  // ---- Layer 3: relu(agg2) -> out (fused log_softmax) ----
  transform3<<<tblocks, 256, 0, stream>>>(agg2, We3, be3, Wr3, b3, yz3p, agg3, N);
  gather4_logsm<<<g4blocks, 256, 0, stream>>>(off, edgeS, yz3p, agg3, out, N);
}

// Round 4
// 663.543 us; speedup vs baseline: 5.0715x; 1.0791x over previous
//
#include <hip/hip_runtime.h>
#include <math.h>

#define D 64
#define NBUCK 98          // buckets of 1024 nodes: bucket = dst >> 10
#define BCAP 24           // LDS staging depth per bucket in partitionK
#define PART_BLOCKS 128

// ---- bf16 pack helpers (RNE) ----
__device__ __forceinline__ unsigned short f2bf(float f) {
  unsigned u = __float_as_uint(f);
  unsigned r = (u + 0x7fff + ((u >> 16) & 1)) >> 16;
  return (unsigned short)r;
}
__device__ __forceinline__ float bfLo(unsigned p) { return __uint_as_float(p << 16); }
__device__ __forceinline__ float bfHi(unsigned p) { return __uint_as_float(p & 0xffff0000u); }
__device__ __forceinline__ unsigned packYZ(float y, float z) {
  return (unsigned)f2bf(y) | ((unsigned)f2bf(z) << 16);
}

// ---------------- transforms (dense per-node GEMMs, wave = 64 output dims) ---

template <bool RELU>
__global__ __launch_bounds__(256) void transform64(
    const float* __restrict__ h, const float* __restrict__ Wm,
    const float* __restrict__ Bm, const float* __restrict__ Wr,
    const float* __restrict__ b, unsigned* __restrict__ yzp,
    float* __restrict__ agg, int n) {
  int wave = (blockIdx.x * 256 + threadIdx.x) >> 6;
  int lane = threadIdx.x & 63;
  int nb = wave << 2;
  if (nb >= n) return;
  float hv[4];
#pragma unroll
  for (int j = 0; j < 4; ++j) {
    int nn = nb + j;
    float v = (nn < n) ? h[(size_t)nn * D + lane] : 0.f;
    if (RELU) v = fmaxf(v, 0.f);
    hv[j] = v;
  }
  float ay[4] = {0.f, 0.f, 0.f, 0.f};
  float az[4] = {0.f, 0.f, 0.f, 0.f};
  float ar[4] = {0.f, 0.f, 0.f, 0.f};
#pragma unroll 8
  for (int k = 0; k < D; ++k) {
    float wm = Wm[k * D + lane];
    float wb = Bm[k * D + lane];
    float wr = Wr[k * D + lane];
#pragma unroll
    for (int j = 0; j < 4; ++j) {
      float hk = __shfl(hv[j], k, 64);
      ay[j] = fmaf(hk, wm, ay[j]);
      az[j] = fmaf(hk, wb, az[j]);
      ar[j] = fmaf(hk, wr, ar[j]);
    }
  }
  float bb = b[lane];
#pragma unroll
  for (int j = 0; j < 4; ++j) {
    int nn = nb + j;
    if (nn >= n) break;
    yzp[(size_t)nn * 64 + lane] = packYZ(ay[j], az[j]);
    agg[(size_t)nn * D + lane] = ar[j] + bb;
  }
}

// Layer 3 transform: lanes 0..3 hold the 4 classes for y,z,r.
__global__ __launch_bounds__(256) void transform3(
    const float* __restrict__ h, const float* __restrict__ Wm,
    const float* __restrict__ Bm, const float* __restrict__ Wr,
    const float* __restrict__ b, unsigned* __restrict__ yz3p,
    float* __restrict__ agg3, int n) {
  int wave = (blockIdx.x * 256 + threadIdx.x) >> 6;
  int lane = threadIdx.x & 63;
  int nb = wave << 2;
  if (nb >= n) return;
  int o = lane & 3;
  float hv[4];
#pragma unroll
  for (int j = 0; j < 4; ++j) {
    int nn = nb + j;
    float v = (nn < n) ? h[(size_t)nn * D + lane] : 0.f;
    hv[j] = fmaxf(v, 0.f);
  }
  float accY[4] = {0.f, 0.f, 0.f, 0.f};
  float accZ[4] = {0.f, 0.f, 0.f, 0.f};
  float accR[4] = {0.f, 0.f, 0.f, 0.f};
#pragma unroll 8
  for (int k = 0; k < D; ++k) {
    float wm = Wm[k * 4 + o];
    float wb = Bm[k * 4 + o];
    float wr = Wr[k * 4 + o];
#pragma unroll
    for (int j = 0; j < 4; ++j) {
      float hk = __shfl(hv[j], k, 64);
      accY[j] = fmaf(hk, wm, accY[j]);
      accZ[j] = fmaf(hk, wb, accZ[j]);
      accR[j] = fmaf(hk, wr, accR[j]);
    }
  }
  if (lane < 4) {
    float bb = b[o];
#pragma unroll
    for (int j = 0; j < 4; ++j) {
      int nn = nb + j;
      if (nn >= n) break;
      yz3p[(size_t)nn * 4 + o] = packYZ(accY[j], accZ[j]);
      agg3[(size_t)nn * 4 + o] = accR[j] + bb;
    }
  }
}

// ---------------- CSR build: bucket hist -> scan -> partition -> place ------

// LDS-preaggregated bucket histogram (98 counters/block -> 98 global atomics).
__global__ __launch_bounds__(256) void subHist(const int* __restrict__ ei,
                                               int* __restrict__ bcnt, int ne) {
  __shared__ int h[NBUCK];
  int t = threadIdx.x;
  if (t < NBUCK) h[t] = 0;
  __syncthreads();
  int stride = gridDim.x * 256;
  for (int e = blockIdx.x * 256 + t; e < ne; e += stride)
    atomicAdd(&h[ei[ne + e] >> 10], 1);
  __syncthreads();
  if (t < NBUCK) atomicAdd(&bcnt[t], h[t]);
}

// 64B-aligned bucket bases (pad each region to a multiple of 8 entries).
__global__ void scanB(const int* __restrict__ bcnt, int* __restrict__ pbase,
                      int* __restrict__ gCur) {
  if (threadIdx.x == 0 && blockIdx.x == 0) {
    int c = 0;
    for (int b = 0; b < NBUCK; ++b) {
      pbase[b] = c;
      gCur[b] = c;
      c += (bcnt[b] + 7) & ~7;
    }
  }
}

// LDS-staged partition: entry = (src | dstLocal<<20, ea_bits). Flushes in
// groups of 8 entries (= one 64B line) per bucket; tails/overflow fall back
// to direct single-entry writes (rare).
__global__ __launch_bounds__(256) void partitionK(
    const int* __restrict__ ei, const float* __restrict__ ea,
    int* __restrict__ gCur, uint2* __restrict__ edgesP, int ne) {
  __shared__ uint2 buf[NBUCK * BCAP];
  __shared__ int cnt[NBUCK];
  int t = threadIdx.x;
  if (t < NBUCK) cnt[t] = 0;
  __syncthreads();
  int chunk = (ne + PART_BLOCKS - 1) / PART_BLOCKS;
  int e0 = blockIdx.x * chunk;
  int e1 = min(ne, e0 + chunk);
  for (int base = e0; base < e1; base += 256) {
    int e = base + t;
    if (e < e1) {
      unsigned s = (unsigned)ei[e];
      int d = ei[ne + e];
      unsigned abits = __float_as_uint(ea[e]);
      int bk = d >> 10;
      unsigned dl = (unsigned)(d & 1023);
      uint2 ent = make_uint2(s | (dl << 20), abits);
      int pos = atomicAdd(&cnt[bk], 1);
      if (pos < BCAP) {
        buf[bk * BCAP + pos] = ent;
      } else {  // overflow fallback (rare)
        int g = atomicAdd(&gCur[bk], 1);
        edgesP[g] = ent;
      }
    }
    __syncthreads();
    if (t < NBUCK) {
      int c = min(cnt[t], BCAP);
      int g8 = c & ~7;
      if (g8) {
        int gb = atomicAdd(&gCur[t], g8);
        for (int i = 0; i < g8; ++i) edgesP[gb + i] = buf[t * BCAP + i];
      }
      int rem = c - g8;
      for (int i = 0; i < rem; ++i) buf[t * BCAP + i] = buf[t * BCAP + g8 + i];
      cnt[t] = rem;
    }
    __syncthreads();
  }
  if (t < NBUCK) {  // final tail flush (<8 entries)
    int c = min(cnt[t], BCAP);
    if (c) {
      int gb = atomicAdd(&gCur[t], c);
      for (int i = 0; i < c; ++i) edgesP[gb + i] = buf[t * BCAP + i];
    }
  }
}

// One block per bucket: local deg hist -> in-block exclusive scan -> emit
// offS/offE (coalesced) -> place edges at exact CSR slots. All scattered
// writes stay inside this block's ~128KB region => full-line write-backs.
__global__ __launch_bounds__(256) void placeK(
    const uint2* __restrict__ edgesP, const int* __restrict__ pbase,
    const int* __restrict__ bcnt, uint2* __restrict__ edgeS,
    int* __restrict__ offS, int* __restrict__ offE, int n) {
  __shared__ int deg[1024];
  __shared__ int cur[1024];
  __shared__ int wsum[4];
  int b = blockIdx.x;
  int t = threadIdx.x;
  int base = pbase[b];
  int cnt = bcnt[b];
  int n0 = b << 10;
  int nn = min(1024, n - n0);
  for (int i = t; i < 1024; i += 256) deg[i] = 0;
  __syncthreads();
  for (int i = t; i < cnt; i += 256)
    atomicAdd(&deg[edgesP[base + i].x >> 20], 1);
  __syncthreads();
  // exclusive scan of deg[0..1023] -> cur
  int v0 = deg[4 * t], v1 = deg[4 * t + 1], v2 = deg[4 * t + 2], v3 = deg[4 * t + 3];
  int t1 = v0 + v1, t2 = t1 + v2, s = t2 + v3;
  int lane = t & 63, wid = t >> 6;
  int inc = s;
#pragma unroll
  for (int d = 1; d < 64; d <<= 1) {
    int u = __shfl_up(inc, d, 64);
    if (lane >= d) inc += u;
  }
  if (lane == 63) wsum[wid] = inc;
  __syncthreads();
  if (t == 0) {
    int a = 0;
#pragma unroll
    for (int w = 0; w < 4; ++w) { int tmp = wsum[w]; wsum[w] = a; a += tmp; }
  }
  __syncthreads();
  int thrOff = wsum[wid] + inc - s;
  cur[4 * t] = thrOff;
  cur[4 * t + 1] = thrOff + v0;
  cur[4 * t + 2] = thrOff + t1;
  cur[4 * t + 3] = thrOff + t2;
  __syncthreads();
  for (int i = t; i < nn; i += 256) {
    int o = base + cur[i];
    offS[n0 + i] = o;
    offE[n0 + i] = o + deg[i];
  }
  __syncthreads();
  for (int i = t; i < cnt; i += 256) {
    uint2 ent = edgesP[base + i];
    int dl = ent.x >> 20;
    int slot = base + atomicAdd(&cur[dl], 1);
    edgeS[slot] = make_uint2(ent.x & 0xFFFFFu, ent.y);
  }
}

// ---------------- gather-aggregate (conflict-free, one write per node) ------

__global__ __launch_bounds__(256) void gather64(
    const int* __restrict__ offS, const int* __restrict__ offE,
    const uint2* __restrict__ edgeS, const unsigned* __restrict__ yzp,
    float* __restrict__ agg, int n) {
  int node = (blockIdx.x * 256 + threadIdx.x) >> 6;
  int lane = threadIdx.x & 63;
  if (node >= n) return;
  int j = offS[node];
  int jend = offE[node];
  float acc = agg[(size_t)node * 64 + lane];
#pragma unroll 1
  for (; j + 3 < jend; j += 4) {
    uint2 e0 = edgeS[j], e1 = edgeS[j + 1], e2 = edgeS[j + 2], e3 = edgeS[j + 3];
    unsigned p0 = yzp[(size_t)e0.x * 64 + lane];
    unsigned p1 = yzp[(size_t)e1.x * 64 + lane];
    unsigned p2 = yzp[(size_t)e2.x * 64 + lane];
    unsigned p3 = yzp[(size_t)e3.x * 64 + lane];
    acc += fmaf(__uint_as_float(e0.y), bfLo(p0), bfHi(p0));
    acc += fmaf(__uint_as_float(e1.y), bfLo(p1), bfHi(p1));
    acc += fmaf(__uint_as_float(e2.y), bfLo(p2), bfHi(p2));
    acc += fmaf(__uint_as_float(e3.y), bfLo(p3), bfHi(p3));
  }
#pragma unroll 1
  for (; j < jend; ++j) {
    uint2 e0 = edgeS[j];
    unsigned p0 = yzp[(size_t)e0.x * 64 + lane];
    acc += fmaf(__uint_as_float(e0.y), bfLo(p0), bfHi(p0));
  }
  agg[(size_t)node * 64 + lane] = acc;
}

// Layer 3: 4 lanes per node (o = class), fused log_softmax across the group.
__global__ __launch_bounds__(256) void gather4_logsm(
    const int* __restrict__ offS, const int* __restrict__ offE,
    const uint2* __restrict__ edgeS, const unsigned* __restrict__ yz3p,
    const float* __restrict__ agg3, float* __restrict__ out, int n) {
  int idx = blockIdx.x * 256 + threadIdx.x;
  int node = idx >> 2;
  int o = idx & 3;
  if (node >= n) return;
  int j = offS[node];
  int jend = offE[node];
  float acc = agg3[(size_t)node * 4 + o];
#pragma unroll 1
  for (; j < jend; ++j) {
    uint2 ed = edgeS[j];
    unsigned p = yz3p[(size_t)ed.x * 4 + o];
    acc += fmaf(__uint_as_float(ed.y), bfLo(p), bfHi(p));
  }
  float m = acc;
  m = fmaxf(m, __shfl_xor(m, 1, 4));
  m = fmaxf(m, __shfl_xor(m, 2, 4));
  float s = expf(acc - m);
  s += __shfl_xor(s, 1, 4);
  s += __shfl_xor(s, 2, 4);
  out[(size_t)node * 4 + o] = acc - m - logf(s);
}

// ---------------- launch -----------------------------------------------------

extern "C" void kernel_launch(void* const* d_in, const int* in_sizes, int n_in,
                              void* d_out, int out_size, void* d_ws, size_t ws_size,
                              hipStream_t stream) {
  const float* x = (const float*)d_in[0];
  const int* ei = (const int*)d_in[1];
  const float* ea = (const float*)d_in[2];
  const float* We1 = (const float*)d_in[3];
  const float* be1 = (const float*)d_in[4];
  const float* Wr1 = (const float*)d_in[5];
  const float* b1 = (const float*)d_in[6];
  const float* We2 = (const float*)d_in[7];
  const float* be2 = (const float*)d_in[8];
  const float* Wr2 = (const float*)d_in[9];
  const float* b2 = (const float*)d_in[10];
  const float* We3 = (const float*)d_in[11];
  const float* be3 = (const float*)d_in[12];
  const float* Wr3 = (const float*)d_in[13];
  const float* b3 = (const float*)d_in[14];

  const int N = in_sizes[0] / D;  // 100000
  const int E = in_sizes[2];      // 1600000
  const size_t EPAD = (size_t)E + 8 * NBUCK;

  // ws layout (8B-aligned regions). edgesP aliases agg2 (dead by the time
  // agg2 is written); agg3/yz3p alias agg1 (dead after layer-2 transform).
  char* ws = (char*)d_ws;
  uint2* edgeS = (uint2*)ws;                                 // EPAD * 8B
  unsigned* yzp = (unsigned*)(ws + EPAD * 8);                // N*64 * 4B
  float* agg1 = (float*)((char*)yzp + (size_t)N * 64 * 4);   // N*64
  float* agg2 = agg1 + (size_t)N * 64;                       // N*64
  int* offS = (int*)(agg2 + (size_t)N * 64);                 // N
  int* offE = offS + N;                                      // N
  int* bcnt = offE + N;                                      // 128
  int* pbase = bcnt + 128;                                   // 128
  int* gCur = pbase + 128;                                   // 128
  uint2* edgesP = (uint2*)agg2;                              // alias
  float* agg3 = agg1;                                        // alias
  unsigned* yz3p = (unsigned*)(agg1 + (size_t)N * 4);        // alias
  float* out = (float*)d_out;

  int waves = (N + 3) / 4;
  int tblocks = (waves + 3) / 4;  // transform: 4 waves/block
  int g64blocks = (int)(((long long)N * 64 + 255) / 256);
  int g4blocks = (int)(((long long)N * 4 + 255) / 256);

  // ---- CSR build ----
  hipMemsetAsync(bcnt, 0, 128 * 4, stream);
  subHist<<<256, 256, 0, stream>>>(ei, bcnt, E);
  scanB<<<1, 64, 0, stream>>>(bcnt, pbase, gCur);
  partitionK<<<PART_BLOCKS, 256, 0, stream>>>(ei, ea, gCur, edgesP, E);
  placeK<<<NBUCK, 256, 0, stream>>>(edgesP, pbase, bcnt, edgeS, offS, offE, N);

  // ---- Layer 1: x -> agg1 ----
  transform64<false><<<tblocks, 256, 0, stream>>>(x, We1, be1, Wr1, b1, yzp, agg1, N);
  gather64<<<g64blocks, 256, 0, stream>>>(offS, offE, edgeS, yzp, agg1, N);
  // ---- Layer 2: relu(agg1) -> agg2 ----
  transform64<true><<<tblocks, 256, 0, stream>>>(agg1, We2, be2, Wr2, b2, yzp, agg2, N);
  gather64<<<g64blocks, 256, 0, stream>>>(offS, offE, edgeS, yzp, agg2, N);
  // ---- Layer 3: relu(agg2) -> out (fused log_softmax) ----
  transform3<<<tblocks, 256, 0, stream>>>(agg2, We3, be3, Wr3, b3, yz3p, agg3, N);
  gather4_logsm<<<g4blocks, 256, 0, stream>>>(offS, offE, edgeS, yz3p, agg3, out, N);
}